// Round 3
// baseline (489.384 us; speedup 1.0000x reference)
//
#include <hip/hip_runtime.h>
#include <math.h>

#define BB 2
#define CIN 256
#define COUT 128
#define LL 4096
#define DI 256
#define DS 16

#define SC_T 32     // chunk length
#define SC_NC 128   // chunks (SC_T*SC_NC == LL)

__device__ __forceinline__ float silu_(float x){ return x / (1.f + expf(-x)); }
__device__ __forceinline__ float sigm_(float x){ return 1.f / (1.f + expf(-x)); }

// ---------- W_eff[p][c][o] = sum_i w_up[c,i,p>>1,p&1] * w_fuse[i,o] ----------
__global__ void k_weff(const float* __restrict__ w_up, const float* __restrict__ w_fuse,
                       float* __restrict__ W_eff){
  int idx = blockIdx.x * 256 + threadIdx.x;   // 4*256*128
  int o = idx & 127;
  int c = (idx >> 7) & 255;
  int p = idx >> 15;
  int kh = p >> 1, kw = p & 1;
  float acc = 0.f;
  #pragma unroll 8
  for (int i = 0; i < COUT; ++i)
    acc += w_up[((c * COUT + i) * 2 + kh) * 2 + kw] * w_fuse[i * COUT + o];
  W_eff[idx] = acc;
}

// ---------- all weight transposes in one kernel ----------
__global__ void k_tr_all(const float* __restrict__ gW_in, const float* __restrict__ gW_gate,
                         const float* __restrict__ gW_out, const float* __restrict__ m_Win,
                         const float* __restrict__ m_Wout,
                         float* __restrict__ gW_inT, float* __restrict__ gW_gateT,
                         float* __restrict__ gW_outT, float* __restrict__ m_WinT,
                         float* __restrict__ m_WoutT){
  int idx = blockIdx.x * 256 + threadIdx.x;   // 147456 total
  if (idx < 16384){ int r = idx >> 7, c = idx & 127; gW_inT[c * 128 + r] = gW_in[idx]; }
  else if (idx < 32768){ int i = idx - 16384; int r = i >> 7, c = i & 127; gW_gateT[c * 128 + r] = gW_gate[i]; }
  else if (idx < 49152){ int i = idx - 32768; int r = i >> 7, c = i & 127; gW_outT[c * 128 + r] = gW_out[i]; }
  else if (idx < 114688){ int i = idx - 49152; int r = i >> 7, c = i & 127; m_WinT[c * 512 + r] = m_Win[i]; }
  else if (idx < 147456){ int i = idx - 114688; int r = i >> 8, c = i & 255; m_WoutT[c * 128 + r] = m_Wout[i]; }
}

// ---------- fused tokens (b,l,o) + per-block channel partial stats ----------
__global__ void k_fused(const float* __restrict__ inp, const float* __restrict__ skip,
                        const float* __restrict__ W_eff, const float* __restrict__ w_fuse,
                        float* __restrict__ fusedT, float* __restrict__ partials1){
  int bid = blockIdx.x;            // b*256 + h*4 + wt
  int wt = bid & 3;
  int h  = (bid >> 2) & 63;
  int b  = bid >> 8;
  int t  = threadIdx.x;            // 256
  int o  = t & 127;
  int wp = t >> 7;

  __shared__ float sIn[256 * 8];
  __shared__ float sSk[128 * 16];
  int hi = h >> 1;
  int wi0 = wt * 8;
  #pragma unroll
  for (int k = 0; k < 8; ++k){
    int e = k * 256 + t;
    int c = e >> 3, wl = e & 7;
    sIn[e] = inp[((b * 256 + c) * 32 + hi) * 32 + wi0 + wl];
  }
  #pragma unroll
  for (int k = 0; k < 8; ++k){
    int e = k * 256 + t;
    int i = e >> 4, wl2 = e & 15;
    sSk[e] = skip[((b * 128 + i) * 64 + h) * 64 + wt * 16 + wl2];
  }
  __syncthreads();

  float acc[8];
  #pragma unroll
  for (int j = 0; j < 8; ++j) acc[j] = 0.f;

  for (int par = 0; par < 2; ++par){
    int p = (h & 1) * 2 + par;
    const float* wptr = W_eff + (size_t)p * 256 * 128 + o;
    for (int c = 0; c < 256; ++c){
      float we = wptr[c * 128];
      #pragma unroll
      for (int jj = 0; jj < 4; ++jj){
        int j = jj * 2 + par;
        int wl = (wp * 8 + j) >> 1;
        acc[j] += sIn[c * 8 + wl] * we;
      }
    }
  }
  for (int i = 0; i < 128; ++i){
    float wf = w_fuse[(128 + i) * 128 + o];
    #pragma unroll
    for (int j = 0; j < 8; ++j)
      acc[j] += sSk[i * 16 + wp * 8 + j] * wf;
  }
  float s8 = 0.f, q8 = 0.f;
  #pragma unroll
  for (int j = 0; j < 8; ++j){
    int w = wt * 16 + wp * 8 + j;
    fusedT[((size_t)(b * 4096 + h * 64 + w)) * 128 + o] = acc[j];
    s8 += acc[j]; q8 += acc[j] * acc[j];
  }
  __shared__ float sS[256], sQ[256];
  sS[t] = s8; sQ[t] = q8;
  __syncthreads();
  if (t < 128){
    partials1[bid * 256 + t * 2]     = sS[t] + sS[t + 128];
    partials1[bid * 256 + t * 2 + 1] = sQ[t] + sQ[t + 128];
  }
}

// ---------- reduce partials -> mu, rs (grid=2 blocks, 128 thr) ----------
__global__ void k_stats2(const float* __restrict__ partials, int nb, float cnt,
                         float* __restrict__ mu, float* __restrict__ rs){
  int b = blockIdx.x;
  int c = threadIdx.x;   // 128
  float S = 0.f, Q = 0.f;
  for (int k = 0; k < nb; ++k){
    S += partials[(size_t)(b * nb + k) * 256 + c * 2];
    Q += partials[(size_t)(b * nb + k) * 256 + c * 2 + 1];
  }
  float m = S / cnt;
  mu[b * 128 + c] = m;
  rs[b * 128 + c] = rsqrtf(Q / cnt - m * m + 1e-5f);
}

// ---------- tok: norm+leaky(x) -> tok2, z, LN -> tb   (32-token tiles) ----------
__global__ void k_tok(const float* __restrict__ xt, const float* __restrict__ mu1,
                      const float* __restrict__ rs1,
                      const float* __restrict__ gW_inT, const float* __restrict__ gW_gateT,
                      const float* __restrict__ gb_gate,
                      const float* __restrict__ ln_g, const float* __restrict__ ln_b,
                      float* __restrict__ tok2, float* __restrict__ zb, float* __restrict__ tb){
  int tok0 = blockIdx.x * 32;
  int b = tok0 >> 12;
  int t = threadIdx.x;
  __shared__ float xnT[128 * 36];   // [c][36]
  __shared__ float aT[32 * 133];    // [tok][133]
  __shared__ float redS[256], redQ[256];
  __shared__ float sMu[32], sRs[32];

  #pragma unroll
  for (int k = 0; k < 16; ++k){
    int e = k * 256 + t;
    int tok = e >> 7, c = e & 127;
    float v = xt[(size_t)(tok0 + tok) * 128 + c];
    v = (v - mu1[b * 128 + c]) * rs1[b * 128 + c];
    v = v >= 0.f ? v : 0.01f * v;
    xnT[c * 36 + tok] = v;
  }
  __syncthreads();

  int o = t & 127, tg = t >> 7;     // 16 toks per thread
  float accA[16], accG[16];
  #pragma unroll
  for (int j = 0; j < 16; ++j){ accA[j] = 0.f; accG[j] = 0.f; }
  for (int c = 0; c < 128; ++c){
    float wa = gW_inT[c * 128 + o];
    float wg = gW_gateT[c * 128 + o];
    const float4* xp = (const float4*)&xnT[c * 36 + tg * 16];
    #pragma unroll
    for (int q = 0; q < 4; ++q){
      float4 x = xp[q];
      accA[q*4+0] += x.x * wa; accA[q*4+1] += x.y * wa; accA[q*4+2] += x.z * wa; accA[q*4+3] += x.w * wa;
      accG[q*4+0] += x.x * wg; accG[q*4+1] += x.y * wg; accG[q*4+2] += x.z * wg; accG[q*4+3] += x.w * wg;
    }
  }
  float gb = gb_gate[o];
  #pragma unroll
  for (int j = 0; j < 16; ++j){
    int tok = tg * 16 + j;
    tok2[(size_t)(tok0 + tok) * 128 + o] = accA[j];
    float g = accG[j] + gb;
    zb[(size_t)(tok0 + tok) * 128 + o] = sigm_(silu_(g));
    aT[tok * 133 + o] = accA[j];
  }
  __syncthreads();
  {
    int tok = t & 31, r = t >> 5;   // 8 o-groups of 16
    float s = 0.f, q = 0.f;
    #pragma unroll
    for (int j = 0; j < 16; ++j){ float a = aT[tok * 133 + r * 16 + j]; s += a; q += a * a; }
    redS[r * 32 + tok] = s; redQ[r * 32 + tok] = q;
  }
  __syncthreads();
  if (t < 32){
    float S = 0.f, Q = 0.f;
    #pragma unroll
    for (int r = 0; r < 8; ++r){ S += redS[r * 32 + t]; Q += redQ[r * 32 + t]; }
    float m = S / 128.f;
    sMu[t] = m; sRs[t] = rsqrtf(Q / 128.f - m * m + 1e-5f);
  }
  __syncthreads();
  #pragma unroll
  for (int k = 0; k < 16; ++k){
    int e = k * 256 + t;
    int tok = e >> 7, c = e & 127;
    float a = aT[tok * 133 + c];
    tb[(size_t)(tok0 + tok) * 128 + c] = (a - sMu[tok]) * sRs[tok] * ln_g[c] + ln_b[c];
  }
}

// ---------- xz: tb @ m_WinT -> xm, silu -> zs  (32-token tiles) ----------
__global__ void k_xz(const float* __restrict__ tb, const float* __restrict__ m_WinT,
                     float* __restrict__ xm, float* __restrict__ zs){
  int tok0 = blockIdx.x * 32;
  int t = threadIdx.x;
  __shared__ float tT[128 * 36];
  #pragma unroll
  for (int k = 0; k < 16; ++k){
    int e = k * 256 + t;
    int tok = e >> 7, c = e & 127;
    tT[c * 36 + tok] = tb[(size_t)(tok0 + tok) * 128 + c];
  }
  __syncthreads();
  for (int half = 0; half < 2; ++half){
    int n = half * 256 + t;
    float acc[32];
    #pragma unroll
    for (int j = 0; j < 32; ++j) acc[j] = 0.f;
    for (int c = 0; c < 128; ++c){
      float w = m_WinT[c * 512 + n];
      const float4* xp = (const float4*)&tT[c * 36];
      #pragma unroll
      for (int q = 0; q < 8; ++q){
        float4 x = xp[q];
        acc[q*4+0] += x.x * w; acc[q*4+1] += x.y * w; acc[q*4+2] += x.z * w; acc[q*4+3] += x.w * w;
      }
    }
    if (half == 0){
      #pragma unroll
      for (int j = 0; j < 32; ++j) xm[(size_t)(tok0 + j) * 256 + t] = acc[j];
    } else {
      #pragma unroll
      for (int j = 0; j < 32; ++j) zs[(size_t)(tok0 + j) * 256 + t] = silu_(acc[j]);
    }
  }
}

// ---------- causal depthwise conv + silu ----------
__global__ void k_conv(const float* __restrict__ xm, const float* __restrict__ cw,
                       const float* __restrict__ cb, float* __restrict__ xc){
  int tok = blockIdx.x;
  int b = tok >> 12;
  int l = tok & 4095;
  int d = threadIdx.x;
  float acc = cb[d];
  #pragma unroll
  for (int k = 0; k < 4; ++k){
    int ls = l - 3 + k;
    if (ls >= 0) acc += xm[((size_t)(b * 4096 + ls)) * 256 + d] * cw[d * 4 + k];
  }
  xc[(size_t)tok * 256 + d] = silu_(acc);
}

// ---------- x_dbl -> dt (softplus), Bm, Cm ----------
__global__ void k_xdbl(const float* __restrict__ xc, const float* __restrict__ m_Wx,
                       const float* __restrict__ m_Wdt, const float* __restrict__ m_bdt,
                       float* __restrict__ dtb, float* __restrict__ Bmb, float* __restrict__ Cmb){
  int tok = blockIdx.x;
  int t = threadIdx.x;   // 256
  __shared__ float sxc[256];
  __shared__ float sdbl[40];
  sxc[t] = xc[(size_t)tok * 256 + t];
  __syncthreads();
  if (t < 40){
    float a = 0.f;
    #pragma unroll 8
    for (int c = 0; c < 256; ++c) a += sxc[c] * m_Wx[t * 256 + c];
    sdbl[t] = a;
  }
  __syncthreads();
  float dtr = m_bdt[t];
  #pragma unroll
  for (int r = 0; r < 8; ++r) dtr += sdbl[r] * m_Wdt[t * 8 + r];
  float sp = (dtr > 20.f) ? dtr : log1pf(expf(dtr));
  dtb[(size_t)tok * 256 + t] = sp;
  if (t < 16)       Bmb[(size_t)tok * 16 + t]        = sdbl[8 + t];
  else if (t < 32)  Cmb[(size_t)tok * 16 + (t - 16)] = sdbl[24 + (t - 16)];
}

// ---------- scan pass A: per-d thread, 16 states in registers ----------
__global__ void k_scanA(const float* __restrict__ dtb, const float* __restrict__ xcb,
                        const float* __restrict__ Bmb, const float* __restrict__ m_Alog,
                        float* __restrict__ chunkA, float* __restrict__ chunkH){
  int c = blockIdx.x & (SC_NC - 1), b = blockIdx.x >> 7;
  int d = threadIdx.x;
  int l0 = c * SC_T;
  __shared__ float sB[SC_T * 16];
  for (int k = threadIdx.x; k < SC_T * 16; k += 256)
    sB[k] = Bmb[((size_t)(b * LL + l0)) * 16 + k];
  __syncthreads();
  float A[16], h[16];
  #pragma unroll
  for (int s = 0; s < 16; ++s){ A[s] = -expf(m_Alog[d * 16 + s]); h[s] = 0.f; }
  float sumdt = 0.f;
  const float* dtp = dtb + ((size_t)(b * LL + l0)) * 256 + d;
  const float* xcp = xcb + ((size_t)(b * LL + l0)) * 256 + d;
  #pragma unroll 4
  for (int l = 0; l < SC_T; ++l){
    float dt = dtp[l * 256];
    float xc = xcp[l * 256];
    sumdt += dt;
    float u = dt * xc;
    const float4* bp = (const float4*)&sB[l * 16];
    float4 b0 = bp[0], b1 = bp[1], b2 = bp[2], b3 = bp[3];
    float bv[16] = {b0.x,b0.y,b0.z,b0.w, b1.x,b1.y,b1.z,b1.w,
                    b2.x,b2.y,b2.z,b2.w, b3.x,b3.y,b3.z,b3.w};
    #pragma unroll
    for (int s = 0; s < 16; ++s)
      h[s] = expf(dt * A[s]) * h[s] + u * bv[s];
  }
  size_t base = ((size_t)(b * SC_NC + c)) * 4096 + d * 16;
  #pragma unroll
  for (int s = 0; s < 16; ++s){
    chunkA[base + s] = expf(A[s] * sumdt);
    chunkH[base + s] = h[s];
  }
}

// ---------- scan pass B: serial combine over chunks ----------
__global__ void k_scanB(const float* __restrict__ chunkA, const float* __restrict__ chunkH,
                        float* __restrict__ carryBuf){
  int gid = blockIdx.x * 256 + threadIdx.x;  // 8192
  int ds = gid & 4095;
  int b = gid >> 12;
  float carry = 0.f;
  #pragma unroll 4
  for (int c = 0; c < SC_NC; ++c){
    size_t idx = ((size_t)(b * SC_NC + c)) * 4096 + ds;
    carryBuf[idx] = carry;
    carry = chunkA[idx] * carry + chunkH[idx];
  }
}

// ---------- scan pass C: re-scan with carry; y = sum_s h*C + xc*D, * silu(zm) ----------
__global__ void k_scanC(const float* __restrict__ dtb, const float* __restrict__ xcb,
                        const float* __restrict__ Bmb, const float* __restrict__ Cmb,
                        const float* __restrict__ m_Alog, const float* __restrict__ m_D,
                        const float* __restrict__ zs, const float* __restrict__ carryBuf,
                        float* __restrict__ yb){
  int c = blockIdx.x & (SC_NC - 1), b = blockIdx.x >> 7;
  int d = threadIdx.x;
  int l0 = c * SC_T;
  __shared__ float sB[SC_T * 16], sC[SC_T * 16];
  for (int k = threadIdx.x; k < SC_T * 16; k += 256){
    sB[k] = Bmb[((size_t)(b * LL + l0)) * 16 + k];
    sC[k] = Cmb[((size_t)(b * LL + l0)) * 16 + k];
  }
  __syncthreads();
  float A[16], h[16];
  size_t cbase = ((size_t)(b * SC_NC + c)) * 4096 + d * 16;
  #pragma unroll
  for (int s = 0; s < 16; ++s){
    A[s] = -expf(m_Alog[d * 16 + s]);
    h[s] = carryBuf[cbase + s];
  }
  float Dv = m_D[d];
  const float* dtp = dtb + ((size_t)(b * LL + l0)) * 256 + d;
  const float* xcp = xcb + ((size_t)(b * LL + l0)) * 256 + d;
  const float* zp  = zs  + ((size_t)(b * LL + l0)) * 256 + d;
  float* yp        = yb  + ((size_t)(b * LL + l0)) * 256 + d;
  #pragma unroll 4
  for (int l = 0; l < SC_T; ++l){
    float dt = dtp[l * 256];
    float xc = xcp[l * 256];
    float zv = zp[l * 256];
    float u = dt * xc;
    const float4* bp = (const float4*)&sB[l * 16];
    const float4* cp = (const float4*)&sC[l * 16];
    float4 b0 = bp[0], b1 = bp[1], b2 = bp[2], b3 = bp[3];
    float4 c0 = cp[0], c1 = cp[1], c2 = cp[2], c3 = cp[3];
    float bv[16] = {b0.x,b0.y,b0.z,b0.w, b1.x,b1.y,b1.z,b1.w,
                    b2.x,b2.y,b2.z,b2.w, b3.x,b3.y,b3.z,b3.w};
    float cv[16] = {c0.x,c0.y,c0.z,c0.w, c1.x,c1.y,c1.z,c1.w,
                    c2.x,c2.y,c2.z,c2.w, c3.x,c3.y,c3.z,c3.w};
    float y = 0.f;
    #pragma unroll
    for (int s = 0; s < 16; ++s){
      h[s] = expf(dt * A[s]) * h[s] + u * bv[s];
      y += h[s] * cv[s];
    }
    yp[l * 256] = (y + xc * Dv) * zv;
  }
}

// ---------- mout + outpre fused (32-token tiles) + IN2 partial stats ----------
__global__ void k_moutpre(const float* __restrict__ yb, const float* __restrict__ m_WoutT,
                          const float* __restrict__ zb, const float* __restrict__ gW_outT,
                          const float* __restrict__ xt, const float* __restrict__ tok2,
                          const float* __restrict__ mu1, const float* __restrict__ rs1,
                          float* __restrict__ outpre, float* __restrict__ partials2){
  int tile = blockIdx.x;
  int tok0 = tile * 32;
  int b = tok0 >> 12;
  int t = threadIdx.x;
  __shared__ float yT[256 * 36];   // [d][36], reused as svT [c][36]
  __shared__ float sS[256], sQ[256];
  #pragma unroll
  for (int k = 0; k < 32; ++k){
    int e = k * 256 + t;
    int tok = e >> 8, dd = e & 255;
    yT[dd * 36 + tok] = yb[(size_t)(tok0 + tok) * 256 + dd];
  }
  __syncthreads();
  int cc = t & 127, tg = t >> 7;   // 16 toks per thread
  float acc[16];
  #pragma unroll
  for (int j = 0; j < 16; ++j) acc[j] = 0.f;
  for (int dd = 0; dd < 256; ++dd){
    float w = m_WoutT[dd * 128 + cc];
    const float4* yp = (const float4*)&yT[dd * 36 + tg * 16];
    #pragma unroll
    for (int q = 0; q < 4; ++q){
      float4 y = yp[q];
      acc[q*4+0] += y.x * w; acc[q*4+1] += y.y * w; acc[q*4+2] += y.z * w; acc[q*4+3] += y.w * w;
    }
  }
  __syncthreads();
  float* svT = yT;
  #pragma unroll
  for (int j = 0; j < 16; ++j){
    int tok = tg * 16 + j;
    float z = zb[(size_t)(tok0 + tok) * 128 + cc];
    svT[cc * 36 + tok] = acc[j] * z;
  }
  __syncthreads();
  float acc2[16];
  #pragma unroll
  for (int j = 0; j < 16; ++j) acc2[j] = 0.f;
  for (int ci = 0; ci < 128; ++ci){
    float w = gW_outT[ci * 128 + cc];
    const float4* sp = (const float4*)&svT[ci * 36 + tg * 16];
    #pragma unroll
    for (int q = 0; q < 4; ++q){
      float4 s = sp[q];
      acc2[q*4+0] += s.x * w; acc2[q*4+1] += s.y * w; acc2[q*4+2] += s.z * w; acc2[q*4+3] += s.w * w;
    }
  }
  float mu = mu1[b * 128 + cc], rsg = rs1[b * 128 + cc];
  float ps = 0.f, pq = 0.f;
  #pragma unroll
  for (int j = 0; j < 16; ++j){
    int tok = tok0 + tg * 16 + j;
    size_t idx = (size_t)tok * 128 + cc;
    float x = xt[idx];
    float xn = (x - mu) * rsg;
    xn = xn >= 0.f ? xn : 0.01f * xn;
    float v = xn + tok2[idx] + acc2[j];
    outpre[idx] = v;
    ps += v; pq += v * v;
  }
  sS[t] = ps; sQ[t] = pq;
  __syncthreads();
  if (t < 128){
    partials2[tile * 256 + t * 2]     = sS[t] + sS[t + 128];
    partials2[tile * 256 + t * 2 + 1] = sQ[t] + sQ[t + 128];
  }
}

// ---------- final: instance-norm + NCHW transpose via LDS ----------
__global__ void k_final(const float* __restrict__ outpre, const float* __restrict__ mu,
                        const float* __restrict__ rs, float* __restrict__ out){
  int bid = blockIdx.x;            // b*128 + cg*64 + lg
  int lg = bid & 63, cg = (bid >> 6) & 1, b = bid >> 7;
  int t = threadIdx.x;
  __shared__ float sT[64 * 65];
  int l0 = lg * 64, c0 = cg * 64;
  #pragma unroll
  for (int k = 0; k < 16; ++k){
    int e = k * 256 + t;
    int l = e >> 6, cc = e & 63;
    float v = outpre[(size_t)(b * 4096 + l0 + l) * 128 + c0 + cc];
    v = (v - mu[b * 128 + c0 + cc]) * rs[b * 128 + c0 + cc];
    sT[cc * 65 + l] = v;
  }
  __syncthreads();
  #pragma unroll
  for (int k = 0; k < 16; ++k){
    int e = k * 256 + t;
    int cc = e >> 6, l = e & 63;
    out[((size_t)(b * 128 + c0 + cc)) * 4096 + l0 + l] = sT[cc * 65 + l];
  }
}

extern "C" void kernel_launch(void* const* d_in, const int* in_sizes, int n_in,
                              void* d_out, int out_size, void* d_ws, size_t ws_size,
                              hipStream_t stream){
  const float* inp    = (const float*)d_in[0];
  const float* skip   = (const float*)d_in[1];
  const float* w_up   = (const float*)d_in[2];
  const float* w_fuse = (const float*)d_in[3];
  const float* gW_in  = (const float*)d_in[4];
  const float* gW_gate= (const float*)d_in[5];
  const float* gb_gate= (const float*)d_in[6];
  const float* ln_g   = (const float*)d_in[7];
  const float* ln_b   = (const float*)d_in[8];
  const float* gW_out = (const float*)d_in[9];
  const float* m_Win  = (const float*)d_in[10];
  const float* m_convw= (const float*)d_in[11];
  const float* m_convb= (const float*)d_in[12];
  const float* m_Wx   = (const float*)d_in[13];
  const float* m_Wdt  = (const float*)d_in[14];
  const float* m_bdt  = (const float*)d_in[15];
  const float* m_Alog = (const float*)d_in[16];
  const float* m_D    = (const float*)d_in[17];
  const float* m_Wout = (const float*)d_in[18];
  float* out = (float*)d_out;

  float* ws = (float*)d_ws;
  float* W_eff    = ws;                        // 131072
  float* xt       = W_eff + 131072;            // 1048576 (raw fused tokens)
  float* tok2     = xt + 1048576;              // 1048576
  float* zb       = tok2 + 1048576;            // 1048576
  float* tbuf     = zb + 1048576;              // 1048576 (tb, later outpre)
  float* xmbuf    = tbuf + 1048576;            // 2097152 (xm, later yb)
  float* zs       = xmbuf + 2097152;           // 2097152
  float* xcb      = zs + 2097152;              // 2097152
  float* dtb      = xcb + 2097152;             // 2097152
  float* Bmb      = dtb + 2097152;             // 131072
  float* Cmb      = Bmb + 131072;              // 131072
  float* chunkA   = Cmb + 131072;              // 1048576
  float* chunkH   = chunkA + 1048576;          // 1048576
  float* carryBuf = chunkH + 1048576;          // 1048576
  float* partials1= carryBuf + 1048576;        // 131072
  float* partials2= partials1 + 131072;        // 65536
  float* stats    = partials2 + 65536;         // 1024
  float* gW_inT   = stats + 1024;              // 16384
  float* gW_gateT = gW_inT + 16384;            // 16384
  float* gW_outT  = gW_gateT + 16384;          // 16384
  float* m_WinT   = gW_outT + 16384;           // 65536
  float* m_WoutT  = m_WinT + 65536;            // 32768

  float* mu1 = stats, *rs1 = stats + 256, *mu2 = stats + 512, *rs2 = stats + 768;
  float* tb = tbuf;
  float* outpre = tbuf;    // alias: tb dead after k_xz
  float* xm = xmbuf;
  float* yb = xmbuf;       // alias: xm dead after k_conv

  k_weff<<<512, 256, 0, stream>>>(w_up, w_fuse, W_eff);
  k_tr_all<<<576, 256, 0, stream>>>(gW_in, gW_gate, gW_out, m_Win, m_Wout,
                                    gW_inT, gW_gateT, gW_outT, m_WinT, m_WoutT);

  k_fused<<<512, 256, 0, stream>>>(inp, skip, W_eff, w_fuse, xt, partials1);
  k_stats2<<<2, 128, 0, stream>>>(partials1, 256, 4096.f, mu1, rs1);

  k_tok<<<256, 256, 0, stream>>>(xt, mu1, rs1, gW_inT, gW_gateT, gb_gate, ln_g, ln_b,
                                 tok2, zb, tb);
  k_xz<<<256, 256, 0, stream>>>(tb, m_WinT, xm, zs);
  k_conv<<<8192, 256, 0, stream>>>(xm, m_convw, m_convb, xcb);
  k_xdbl<<<8192, 256, 0, stream>>>(xcb, m_Wx, m_Wdt, m_bdt, dtb, Bmb, Cmb);

  k_scanA<<<256, 256, 0, stream>>>(dtb, xcb, Bmb, m_Alog, chunkA, chunkH);
  k_scanB<<<32, 256, 0, stream>>>(chunkA, chunkH, carryBuf);
  k_scanC<<<256, 256, 0, stream>>>(dtb, xcb, Bmb, Cmb, m_Alog, m_D, zs, carryBuf, yb);

  k_moutpre<<<256, 256, 0, stream>>>(yb, m_WoutT, zb, gW_outT, xt, tok2, mu1, rs1,
                                     outpre, partials2);
  k_stats2<<<2, 128, 0, stream>>>(partials2, 128, 4096.f, mu2, rs2);
  k_final<<<256, 256, 0, stream>>>(outpre, mu2, rs2, out);
}

// Round 4
// 330.557 us; speedup vs baseline: 1.4805x; 1.4805x over previous
//
#include <hip/hip_runtime.h>
#include <math.h>

#define BB 2
#define CIN 256
#define COUT 128
#define LL 4096
#define DI 256
#define DS 16

#define SC_T 16     // chunk length (== k_mid tile)
#define SC_NC 256   // chunks per batch

__device__ __forceinline__ float silu_(float x){ return x / (1.f + expf(-x)); }
__device__ __forceinline__ float sigm_(float x){ return 1.f / (1.f + expf(-x)); }

// ---------- W_eff[p][c][o] = sum_i w_up[c,i,p>>1,p&1] * w_fuse[i,o] ----------
__global__ __launch_bounds__(256) void k_weff(const float* __restrict__ w_up,
                       const float* __restrict__ w_fuse, float* __restrict__ W_eff){
  int idx = blockIdx.x * 256 + threadIdx.x;   // 4*256*128
  int o = idx & 127;
  int c = (idx >> 7) & 255;
  int p = idx >> 15;
  int kh = p >> 1, kw = p & 1;
  float acc = 0.f;
  #pragma unroll 8
  for (int i = 0; i < COUT; ++i)
    acc += w_up[((c * COUT + i) * 2 + kh) * 2 + kw] * w_fuse[i * COUT + o];
  W_eff[idx] = acc;
}

// ---------- weight prep: transposes + m_WxT (k-major) + Aexp ----------
__global__ __launch_bounds__(256) void k_tr_all(
    const float* __restrict__ gW_in, const float* __restrict__ gW_gate,
    const float* __restrict__ gW_out, const float* __restrict__ m_Win,
    const float* __restrict__ m_Wout, const float* __restrict__ m_Wx,
    const float* __restrict__ m_Alog,
    float* __restrict__ gW_inT, float* __restrict__ gW_gateT,
    float* __restrict__ gW_outT, float* __restrict__ m_WinT,
    float* __restrict__ m_WoutT, float* __restrict__ m_WxT,
    float* __restrict__ Aexp){
  int idx = blockIdx.x * 256 + threadIdx.x;   // 161792 total
  if (idx < 16384){ int r = idx >> 7, c = idx & 127; gW_inT[c * 128 + r] = gW_in[idx]; }
  else if (idx < 32768){ int i = idx - 16384; int r = i >> 7, c = i & 127; gW_gateT[c * 128 + r] = gW_gate[i]; }
  else if (idx < 49152){ int i = idx - 32768; int r = i >> 7, c = i & 127; gW_outT[c * 128 + r] = gW_out[i]; }
  else if (idx < 114688){ int i = idx - 49152; int r = i >> 7, c = i & 127; m_WinT[c * 512 + r] = m_Win[i]; }
  else if (idx < 147456){ int i = idx - 114688; int r = i >> 8, c = i & 255; m_WoutT[c * 128 + r] = m_Wout[i]; }
  else if (idx < 157696){ int i = idx - 147456; int o = i >> 8, k = i & 255; m_WxT[k * 40 + o] = m_Wx[i]; }
  else if (idx < 161792){ int i = idx - 157696; Aexp[i] = -expf(m_Alog[i]); }
}

// ---------- fused tokens (b,l,o) + per-block channel partial stats ----------
__global__ __launch_bounds__(256) void k_fused(const float* __restrict__ inp,
                        const float* __restrict__ skip,
                        const float* __restrict__ W_eff, const float* __restrict__ w_fuse,
                        float* __restrict__ fusedT, float* __restrict__ partials1){
  int bid = blockIdx.x;            // b*256 + h*4 + wt
  int wt = bid & 3;
  int h  = (bid >> 2) & 63;
  int b  = bid >> 8;
  int t  = threadIdx.x;            // 256
  int o  = t & 127;
  int wp = t >> 7;

  __shared__ float sIn[256 * 8];
  __shared__ float sSk[128 * 16];
  int hi = h >> 1;
  int wi0 = wt * 8;
  #pragma unroll
  for (int k = 0; k < 8; ++k){
    int e = k * 256 + t;
    int c = e >> 3, wl = e & 7;
    sIn[e] = inp[((b * 256 + c) * 32 + hi) * 32 + wi0 + wl];
  }
  #pragma unroll
  for (int k = 0; k < 8; ++k){
    int e = k * 256 + t;
    int i = e >> 4, wl2 = e & 15;
    sSk[e] = skip[((b * 128 + i) * 64 + h) * 64 + wt * 16 + wl2];
  }
  __syncthreads();

  float acc[8];
  #pragma unroll
  for (int j = 0; j < 8; ++j) acc[j] = 0.f;

  for (int par = 0; par < 2; ++par){
    int p = (h & 1) * 2 + par;
    const float* wptr = W_eff + (size_t)p * 256 * 128 + o;
    for (int c = 0; c < 256; ++c){
      float we = wptr[c * 128];
      #pragma unroll
      for (int jj = 0; jj < 4; ++jj){
        int j = jj * 2 + par;
        int wl = (wp * 8 + j) >> 1;
        acc[j] += sIn[c * 8 + wl] * we;
      }
    }
  }
  for (int i = 0; i < 128; ++i){
    float wf = w_fuse[(128 + i) * 128 + o];
    #pragma unroll
    for (int j = 0; j < 8; ++j)
      acc[j] += sSk[i * 16 + wp * 8 + j] * wf;
  }
  float s8 = 0.f, q8 = 0.f;
  #pragma unroll
  for (int j = 0; j < 8; ++j){
    int w = wt * 16 + wp * 8 + j;
    fusedT[((size_t)(b * 4096 + h * 64 + w)) * 128 + o] = acc[j];
    s8 += acc[j]; q8 += acc[j] * acc[j];
  }
  __shared__ float sS[256], sQ[256];
  sS[t] = s8; sQ[t] = q8;
  __syncthreads();
  if (t < 128){
    partials1[bid * 256 + t * 2]     = sS[t] + sS[t + 128];
    partials1[bid * 256 + t * 2 + 1] = sQ[t] + sQ[t + 128];
  }
}

// ---------- reduce partials -> mu, rs (grid=2, 256 thr) ----------
__global__ __launch_bounds__(256) void k_stats2(const float* __restrict__ partials, int nb,
                         float cnt, float* __restrict__ mu, float* __restrict__ rs){
  int b = blockIdx.x;
  int t = threadIdx.x;
  int c = t & 127, half = t >> 7;
  int n2 = nb >> 1;
  float S = 0.f, Q = 0.f;
  for (int k = half * n2; k < (half + 1) * n2; ++k){
    S += partials[(size_t)(b * nb + k) * 256 + c * 2];
    Q += partials[(size_t)(b * nb + k) * 256 + c * 2 + 1];
  }
  __shared__ float sS[256], sQ[256];
  sS[t] = S; sQ[t] = Q;
  __syncthreads();
  if (t < 128){
    float Sa = sS[t] + sS[t + 128], Qa = sQ[t] + sQ[t + 128];
    float m = Sa / cnt;
    mu[b * 128 + t] = m;
    rs[b * 128 + t] = rsqrtf(Qa / cnt - m * m + 1e-5f);
  }
}

// ---------- front: norm+leaky -> (tok2, z) -> LN -> xz GEMM -> xm, zs ----------
// T=8 tokens per block, grid 1024, 256 threads
__global__ __launch_bounds__(256) void k_front(const float* __restrict__ xt,
                      const float* __restrict__ mu1, const float* __restrict__ rs1,
                      const float* __restrict__ gW_inT, const float* __restrict__ gW_gateT,
                      const float* __restrict__ gb_gate,
                      const float* __restrict__ ln_g, const float* __restrict__ ln_b,
                      const float* __restrict__ m_WinT,
                      float* __restrict__ tok2, float* __restrict__ zb,
                      float* __restrict__ xm, float* __restrict__ zs){
  int tok0 = blockIdx.x * 8;
  int b = tok0 >> 12;
  int t = threadIdx.x;
  __shared__ float xn[128 * 8];    // [c][tok]
  __shared__ float tn[128 * 8];    // [c][tok] normalized-t
  __shared__ float aT[8 * 132];    // [tok][o]
  __shared__ float sMu[8], sRs[8];

  #pragma unroll
  for (int k = 0; k < 4; ++k){
    int e = k * 256 + t;
    int tok = e >> 7, c = e & 127;
    float v = xt[(size_t)(tok0 + tok) * 128 + c];
    v = (v - mu1[b * 128 + c]) * rs1[b * 128 + c];
    v = v >= 0.f ? v : 0.01f * v;
    xn[c * 8 + tok] = v;
  }
  __syncthreads();

  // GEMM1: A = xn@gW_in, G = xn@gW_gate  (thread: o = t&127, th = t>>7 -> toks th*4..+3)
  int o = t & 127, th = t >> 7;
  float accA[4], accG[4];
  #pragma unroll
  for (int j = 0; j < 4; ++j){ accA[j] = 0.f; accG[j] = 0.f; }
  for (int c = 0; c < 128; ++c){
    float wa = gW_inT[c * 128 + o];
    float wg = gW_gateT[c * 128 + o];
    float4 x = *(const float4*)&xn[c * 8 + th * 4];
    accA[0] += x.x * wa; accA[1] += x.y * wa; accA[2] += x.z * wa; accA[3] += x.w * wa;
    accG[0] += x.x * wg; accG[1] += x.y * wg; accG[2] += x.z * wg; accG[3] += x.w * wg;
  }
  float gb = gb_gate[o];
  #pragma unroll
  for (int j = 0; j < 4; ++j){
    int tok = th * 4 + j;
    tok2[(size_t)(tok0 + tok) * 128 + o] = accA[j];
    zb[(size_t)(tok0 + tok) * 128 + o] = sigm_(silu_(accG[j] + gb));
    aT[tok * 132 + o] = accA[j];
  }
  __syncthreads();

  // LN stats: 128 threads = 8 toks x 16 lanes
  if (t < 128){
    int tok = t >> 4, i = t & 15;
    float s = 0.f, q = 0.f;
    #pragma unroll
    for (int j = 0; j < 8; ++j){ float a = aT[tok * 132 + i * 8 + j]; s += a; q += a * a; }
    s += __shfl_down(s, 8, 16); q += __shfl_down(q, 8, 16);
    s += __shfl_down(s, 4, 16); q += __shfl_down(q, 4, 16);
    s += __shfl_down(s, 2, 16); q += __shfl_down(q, 2, 16);
    s += __shfl_down(s, 1, 16); q += __shfl_down(q, 1, 16);
    if (i == 0){
      float m = s / 128.f;
      sMu[tok] = m;
      sRs[tok] = rsqrtf(q / 128.f - m * m + 1e-5f);
    }
  }
  __syncthreads();
  #pragma unroll
  for (int k = 0; k < 4; ++k){
    int e = k * 256 + t;
    int tok = e >> 7, c = e & 127;
    tn[c * 8 + tok] = (aT[tok * 132 + c] - sMu[tok]) * sRs[tok] * ln_g[c] + ln_b[c];
  }
  __syncthreads();

  // GEMM2: xz = tn @ m_WinT ; thread handles n = t (x part) and n = t+256 (z part), 8 toks
  float a0[8], a1[8];
  #pragma unroll
  for (int j = 0; j < 8; ++j){ a0[j] = 0.f; a1[j] = 0.f; }
  for (int c = 0; c < 128; ++c){
    float w0 = m_WinT[c * 512 + t];
    float w1 = m_WinT[c * 512 + 256 + t];
    float4 x0 = *(const float4*)&tn[c * 8];
    float4 x1 = *(const float4*)&tn[c * 8 + 4];
    a0[0] += x0.x * w0; a0[1] += x0.y * w0; a0[2] += x0.z * w0; a0[3] += x0.w * w0;
    a0[4] += x1.x * w0; a0[5] += x1.y * w0; a0[6] += x1.z * w0; a0[7] += x1.w * w0;
    a1[0] += x0.x * w1; a1[1] += x0.y * w1; a1[2] += x0.z * w1; a1[3] += x0.w * w1;
    a1[4] += x1.x * w1; a1[5] += x1.y * w1; a1[6] += x1.z * w1; a1[7] += x1.w * w1;
  }
  #pragma unroll
  for (int j = 0; j < 8; ++j){
    xm[(size_t)(tok0 + j) * 256 + t] = a0[j];
    zs[(size_t)(tok0 + j) * 256 + t] = silu_(a1[j]);
  }
}

// ---------- mid: conv+silu -> x_dbl -> dt/B/C -> scanA (chunk-local) ----------
// tile = chunk SC_T=16; grid 512 (b*256+ch); 256 threads
__global__ __launch_bounds__(256) void k_mid(const float* __restrict__ xm,
                    const float* __restrict__ cw, const float* __restrict__ cb,
                    const float* __restrict__ m_WxT, const float* __restrict__ m_Wdt,
                    const float* __restrict__ m_bdt, const float* __restrict__ Aexp,
                    float* __restrict__ xcb, float* __restrict__ dtb,
                    float* __restrict__ Bmb, float* __restrict__ Cmb,
                    float* __restrict__ chunkA, float* __restrict__ chunkH){
  int ch = blockIdx.x & 255, b = blockIdx.x >> 8;
  int l0 = ch * SC_T;
  int tok0 = b * LL + l0;
  int t = threadIdx.x;
  __shared__ float sxm[19 * 256];
  __shared__ float sxc[16 * 256];
  __shared__ float sdbl[16 * 40];

  #pragma unroll
  for (int r = 0; r < 19; ++r){
    int l = l0 - 3 + r;
    sxm[r * 256 + t] = (l >= 0) ? xm[(size_t)(b * LL + l) * 256 + t] : 0.f;
  }
  __syncthreads();

  // conv (thread = d)
  float cw0 = cw[t * 4], cw1 = cw[t * 4 + 1], cw2 = cw[t * 4 + 2], cw3 = cw[t * 4 + 3];
  float cbv = cb[t];
  float xcr[16];
  #pragma unroll
  for (int j = 0; j < 16; ++j){
    float a = cbv + sxm[j * 256 + t] * cw0 + sxm[(j + 1) * 256 + t] * cw1
                  + sxm[(j + 2) * 256 + t] * cw2 + sxm[(j + 3) * 256 + t] * cw3;
    a = silu_(a);
    xcr[j] = a;
    sxc[j * 256 + t] = a;
    xcb[(size_t)(tok0 + j) * 256 + t] = a;
  }
  __syncthreads();

  // x_dbl: thread = (tok, i): outputs i(<8), 8+i (B), 24+i (C)
  {
    int tok = t >> 4, i = t & 15;
    float acc0 = 0.f, acc1 = 0.f, acc2 = 0.f;
    const float* xcrow = &sxc[tok * 256];
    for (int k = 0; k < 256; ++k){
      float xv = xcrow[k];
      const float* wr = &m_WxT[k * 40];
      acc1 += xv * wr[8 + i];
      acc2 += xv * wr[24 + i];
      if (i < 8) acc0 += xv * wr[i];
    }
    sdbl[tok * 40 + 8 + i] = acc1;
    sdbl[tok * 40 + 24 + i] = acc2;
    if (i < 8) sdbl[tok * 40 + i] = acc0;
    Bmb[(size_t)tok0 * 16 + t] = acc1;   // (tok0+tok)*16 + i
    Cmb[(size_t)tok0 * 16 + t] = acc2;
  }
  __syncthreads();

  // dt + local scan (thread = d)
  float w8[8];
  #pragma unroll
  for (int r = 0; r < 8; ++r) w8[r] = m_Wdt[t * 8 + r];
  float bdt = m_bdt[t];
  float A[16];
  {
    const float4* ap = (const float4*)&Aexp[t * 16];
    float4 a0 = ap[0], a1 = ap[1], a2 = ap[2], a3 = ap[3];
    A[0]=a0.x; A[1]=a0.y; A[2]=a0.z; A[3]=a0.w;
    A[4]=a1.x; A[5]=a1.y; A[6]=a1.z; A[7]=a1.w;
    A[8]=a2.x; A[9]=a2.y; A[10]=a2.z; A[11]=a2.w;
    A[12]=a3.x; A[13]=a3.y; A[14]=a3.z; A[15]=a3.w;
  }
  float h[16];
  #pragma unroll
  for (int s = 0; s < 16; ++s) h[s] = 0.f;
  float sumdt = 0.f;
  #pragma unroll 2
  for (int j = 0; j < 16; ++j){
    float dtr = bdt;
    #pragma unroll
    for (int r = 0; r < 8; ++r) dtr += sdbl[j * 40 + r] * w8[r];
    float dt = (dtr > 20.f) ? dtr : log1pf(expf(dtr));
    dtb[(size_t)(tok0 + j) * 256 + t] = dt;
    sumdt += dt;
    float u = dt * xcr[j];
    const float4* bp = (const float4*)&sdbl[j * 40 + 8];
    float4 b0 = bp[0], b1 = bp[1], b2 = bp[2], b3 = bp[3];
    float bv[16] = {b0.x,b0.y,b0.z,b0.w, b1.x,b1.y,b1.z,b1.w,
                    b2.x,b2.y,b2.z,b2.w, b3.x,b3.y,b3.z,b3.w};
    #pragma unroll
    for (int s = 0; s < 16; ++s)
      h[s] = expf(dt * A[s]) * h[s] + u * bv[s];
  }
  size_t base = ((size_t)(b * SC_NC + ch)) * 4096 + t * 16;
  #pragma unroll
  for (int s = 0; s < 16; ++s){
    chunkA[base + s] = expf(A[s] * sumdt);
    chunkH[base + s] = h[s];
  }
}

// ---------- scanB: serial combine over 256 chunks ----------
__global__ __launch_bounds__(256) void k_scanB(const float* __restrict__ chunkA,
                        const float* __restrict__ chunkH, float* __restrict__ carryBuf){
  int gid = blockIdx.x * 256 + threadIdx.x;  // 8192
  int ds = gid & 4095;
  int b = gid >> 12;
  size_t base = (size_t)b * SC_NC * 4096 + ds;
  float carry = 0.f;
  for (int c = 0; c < SC_NC; c += 4){
    size_t i0 = base + (size_t)c * 4096;
    float A0 = chunkA[i0], H0 = chunkH[i0];
    float A1 = chunkA[i0 + 4096], H1 = chunkH[i0 + 4096];
    float A2 = chunkA[i0 + 8192], H2 = chunkH[i0 + 8192];
    float A3 = chunkA[i0 + 12288], H3 = chunkH[i0 + 12288];
    carryBuf[i0] = carry;           carry = A0 * carry + H0;
    carryBuf[i0 + 4096] = carry;    carry = A1 * carry + H1;
    carryBuf[i0 + 8192] = carry;    carry = A2 * carry + H2;
    carryBuf[i0 + 12288] = carry;   carry = A3 * carry + H3;
  }
}

// ---------- scanC: re-scan with carry; y = sum_s h*C + xc*D, * silu(zm) ----------
__global__ __launch_bounds__(256) void k_scanC(const float* __restrict__ dtb,
                        const float* __restrict__ xcb,
                        const float* __restrict__ Bmb, const float* __restrict__ Cmb,
                        const float* __restrict__ Aexp, const float* __restrict__ m_D,
                        const float* __restrict__ zs, const float* __restrict__ carryBuf,
                        float* __restrict__ yb){
  int ch = blockIdx.x & 255, b = blockIdx.x >> 8;
  int l0 = ch * SC_T;
  int tok0 = b * LL + l0;
  int t = threadIdx.x;
  __shared__ float sB[SC_T * 16], sC[SC_T * 16];
  sB[t] = Bmb[(size_t)tok0 * 16 + t];
  sC[t] = Cmb[(size_t)tok0 * 16 + t];
  __syncthreads();
  float A[16], h[16];
  {
    const float4* ap = (const float4*)&Aexp[t * 16];
    float4 a0 = ap[0], a1 = ap[1], a2 = ap[2], a3 = ap[3];
    A[0]=a0.x; A[1]=a0.y; A[2]=a0.z; A[3]=a0.w;
    A[4]=a1.x; A[5]=a1.y; A[6]=a1.z; A[7]=a1.w;
    A[8]=a2.x; A[9]=a2.y; A[10]=a2.z; A[11]=a2.w;
    A[12]=a3.x; A[13]=a3.y; A[14]=a3.z; A[15]=a3.w;
  }
  size_t cbase = ((size_t)(b * SC_NC + ch)) * 4096 + t * 16;
  {
    const float4* cp = (const float4*)&carryBuf[cbase];
    float4 c0 = cp[0], c1 = cp[1], c2 = cp[2], c3 = cp[3];
    h[0]=c0.x; h[1]=c0.y; h[2]=c0.z; h[3]=c0.w;
    h[4]=c1.x; h[5]=c1.y; h[6]=c1.z; h[7]=c1.w;
    h[8]=c2.x; h[9]=c2.y; h[10]=c2.z; h[11]=c2.w;
    h[12]=c3.x; h[13]=c3.y; h[14]=c3.z; h[15]=c3.w;
  }
  float Dv = m_D[t];
  const float* dtp = dtb + (size_t)tok0 * 256 + t;
  const float* xcp = xcb + (size_t)tok0 * 256 + t;
  const float* zp  = zs  + (size_t)tok0 * 256 + t;
  float* yp        = yb  + (size_t)tok0 * 256 + t;
  #pragma unroll 2
  for (int l = 0; l < SC_T; ++l){
    float dt = dtp[l * 256];
    float xc = xcp[l * 256];
    float zv = zp[l * 256];
    float u = dt * xc;
    const float4* bp = (const float4*)&sB[l * 16];
    const float4* cp = (const float4*)&sC[l * 16];
    float4 b0 = bp[0], b1 = bp[1], b2 = bp[2], b3 = bp[3];
    float4 c0 = cp[0], c1 = cp[1], c2 = cp[2], c3 = cp[3];
    float bv[16] = {b0.x,b0.y,b0.z,b0.w, b1.x,b1.y,b1.z,b1.w,
                    b2.x,b2.y,b2.z,b2.w, b3.x,b3.y,b3.z,b3.w};
    float cv[16] = {c0.x,c0.y,c0.z,c0.w, c1.x,c1.y,c1.z,c1.w,
                    c2.x,c2.y,c2.z,c2.w, c3.x,c3.y,c3.z,c3.w};
    float y = 0.f;
    #pragma unroll
    for (int s = 0; s < 16; ++s){
      h[s] = expf(dt * A[s]) * h[s] + u * bv[s];
      y += h[s] * cv[s];
    }
    yp[l * 256] = (y + xc * Dv) * zv;
  }
}

// ---------- mout + outpre (T=8 tokens, grid 1024) + IN2 partial stats ----------
__global__ __launch_bounds__(256) void k_moutpre(const float* __restrict__ yb,
                          const float* __restrict__ m_WoutT,
                          const float* __restrict__ zb, const float* __restrict__ gW_outT,
                          const float* __restrict__ xt, const float* __restrict__ tok2,
                          const float* __restrict__ mu1, const float* __restrict__ rs1,
                          float* __restrict__ outpre, float* __restrict__ partials2){
  int tile = blockIdx.x;
  int tok0 = tile * 8;
  int b = tok0 >> 12;
  int t = threadIdx.x;
  __shared__ float yT[256 * 8];   // [d][tok]
  __shared__ float sv[128 * 8];   // [c][tok]
  __shared__ float sS[256], sQ[256];
  #pragma unroll
  for (int k = 0; k < 8; ++k){
    int e = k * 256 + t;
    int tok = e >> 8, dd = e & 255;
    yT[dd * 8 + tok] = yb[(size_t)(tok0 + tok) * 256 + dd];
  }
  __syncthreads();
  int cc = t & 127, th = t >> 7;   // 4 toks per thread
  float acc[4];
  #pragma unroll
  for (int j = 0; j < 4; ++j) acc[j] = 0.f;
  for (int dd = 0; dd < 256; ++dd){
    float w = m_WoutT[dd * 128 + cc];
    float4 y = *(const float4*)&yT[dd * 8 + th * 4];
    acc[0] += y.x * w; acc[1] += y.y * w; acc[2] += y.z * w; acc[3] += y.w * w;
  }
  #pragma unroll
  for (int j = 0; j < 4; ++j){
    int tok = th * 4 + j;
    float z = zb[(size_t)(tok0 + tok) * 128 + cc];
    sv[cc * 8 + tok] = acc[j] * z;
  }
  __syncthreads();
  float acc2[4];
  #pragma unroll
  for (int j = 0; j < 4; ++j) acc2[j] = 0.f;
  for (int ci = 0; ci < 128; ++ci){
    float w = gW_outT[ci * 128 + cc];
    float4 s = *(const float4*)&sv[ci * 8 + th * 4];
    acc2[0] += s.x * w; acc2[1] += s.y * w; acc2[2] += s.z * w; acc2[3] += s.w * w;
  }
  float mu = mu1[b * 128 + cc], rsg = rs1[b * 128 + cc];
  float ps = 0.f, pq = 0.f;
  #pragma unroll
  for (int j = 0; j < 4; ++j){
    int tok = tok0 + th * 4 + j;
    size_t idx = (size_t)tok * 128 + cc;
    float x = xt[idx];
    float xn = (x - mu) * rsg;
    xn = xn >= 0.f ? xn : 0.01f * xn;
    float v = xn + tok2[idx] + acc2[j];
    outpre[idx] = v;
    ps += v; pq += v * v;
  }
  sS[t] = ps; sQ[t] = pq;
  __syncthreads();
  if (t < 128){
    partials2[tile * 256 + t * 2]     = sS[t] + sS[t + 128];
    partials2[tile * 256 + t * 2 + 1] = sQ[t] + sQ[t + 128];
  }
}

// ---------- final: instance-norm + NCHW transpose via LDS (grid 512) ----------
__global__ __launch_bounds__(256) void k_final(const float* __restrict__ outpre,
                        const float* __restrict__ mu,
                        const float* __restrict__ rs, float* __restrict__ out){
  int bid = blockIdx.x;            // b*256 + cg*128 + lg
  int lg = bid & 127, cg = (bid >> 7) & 1, b = bid >> 8;
  int t = threadIdx.x;
  __shared__ float sT[64 * 33];
  int l0 = lg * 32, c0 = cg * 64;
  #pragma unroll
  for (int k = 0; k < 8; ++k){
    int e = k * 256 + t;
    int l = e >> 6, cc = e & 63;
    float v = outpre[(size_t)(b * 4096 + l0 + l) * 128 + c0 + cc];
    v = (v - mu[b * 128 + c0 + cc]) * rs[b * 128 + c0 + cc];
    sT[cc * 33 + l] = v;
  }
  __syncthreads();
  #pragma unroll
  for (int k = 0; k < 8; ++k){
    int e = k * 256 + t;
    int cc = e >> 5, l = e & 31;
    out[((size_t)(b * 128 + c0 + cc)) * 4096 + l0 + l] = sT[cc * 33 + l];
  }
}

extern "C" void kernel_launch(void* const* d_in, const int* in_sizes, int n_in,
                              void* d_out, int out_size, void* d_ws, size_t ws_size,
                              hipStream_t stream){
  const float* inp    = (const float*)d_in[0];
  const float* skip   = (const float*)d_in[1];
  const float* w_up   = (const float*)d_in[2];
  const float* w_fuse = (const float*)d_in[3];
  const float* gW_in  = (const float*)d_in[4];
  const float* gW_gate= (const float*)d_in[5];
  const float* gb_gate= (const float*)d_in[6];
  const float* ln_g   = (const float*)d_in[7];
  const float* ln_b   = (const float*)d_in[8];
  const float* gW_out = (const float*)d_in[9];
  const float* m_Win  = (const float*)d_in[10];
  const float* m_convw= (const float*)d_in[11];
  const float* m_convb= (const float*)d_in[12];
  const float* m_Wx   = (const float*)d_in[13];
  const float* m_Wdt  = (const float*)d_in[14];
  const float* m_bdt  = (const float*)d_in[15];
  const float* m_Alog = (const float*)d_in[16];
  const float* m_D    = (const float*)d_in[17];
  const float* m_Wout = (const float*)d_in[18];
  float* out = (float*)d_out;

  float* ws = (float*)d_ws;
  float* W_eff    = ws;                        // 131072
  float* xt       = W_eff + 131072;            // 1048576
  float* tok2     = xt + 1048576;              // 1048576
  float* zb       = tok2 + 1048576;            // 1048576
  float* xmbuf    = zb + 1048576;              // 2097152 (xm, later yb)
  float* zsbuf    = xmbuf + 2097152;           // 2097152 (zs, later outpre)
  float* xcb      = zsbuf + 2097152;           // 2097152
  float* dtb      = xcb + 2097152;             // 2097152
  float* Bmb      = dtb + 2097152;             // 131072
  float* Cmb      = Bmb + 131072;              // 131072
  float* chunkA   = Cmb + 131072;              // 2097152
  float* chunkH   = chunkA + 2097152;          // 2097152
  float* carryBuf = chunkH + 2097152;          // 2097152
  float* partials1= carryBuf + 2097152;        // 131072
  float* partials2= partials1 + 131072;        // 262144
  float* stats    = partials2 + 262144;        // 1024
  float* gW_inT   = stats + 1024;              // 16384
  float* gW_gateT = gW_inT + 16384;            // 16384
  float* gW_outT  = gW_gateT + 16384;          // 16384
  float* m_WinT   = gW_outT + 16384;           // 65536
  float* m_WoutT  = m_WinT + 65536;            // 32768
  float* m_WxT    = m_WoutT + 32768;           // 10240
  float* AexpBuf  = m_WxT + 10240;             // 4096

  float* mu1 = stats, *rs1 = stats + 256, *mu2 = stats + 512, *rs2 = stats + 768;
  float* xm = xmbuf;
  float* yb = xmbuf;       // alias: xm dead after k_mid
  float* zs = zsbuf;
  float* outpre = zsbuf;   // alias: zs dead after k_scanC

  k_weff<<<512, 256, 0, stream>>>(w_up, w_fuse, W_eff);
  k_tr_all<<<632, 256, 0, stream>>>(gW_in, gW_gate, gW_out, m_Win, m_Wout, m_Wx, m_Alog,
                                    gW_inT, gW_gateT, gW_outT, m_WinT, m_WoutT, m_WxT,
                                    AexpBuf);

  k_fused<<<512, 256, 0, stream>>>(inp, skip, W_eff, w_fuse, xt, partials1);
  k_stats2<<<2, 256, 0, stream>>>(partials1, 256, 4096.f, mu1, rs1);

  k_front<<<1024, 256, 0, stream>>>(xt, mu1, rs1, gW_inT, gW_gateT, gb_gate, ln_g, ln_b,
                                    m_WinT, tok2, zb, xm, zs);
  k_mid<<<512, 256, 0, stream>>>(xm, m_convw, m_convb, m_WxT, m_Wdt, m_bdt, AexpBuf,
                                 xcb, dtb, Bmb, Cmb, chunkA, chunkH);
  k_scanB<<<32, 256, 0, stream>>>(chunkA, chunkH, carryBuf);
  k_scanC<<<512, 256, 0, stream>>>(dtb, xcb, Bmb, Cmb, AexpBuf, m_D, zs, carryBuf, yb);

  k_moutpre<<<1024, 256, 0, stream>>>(yb, m_WoutT, zb, gW_outT, xt, tok2, mu1, rs1,
                                      outpre, partials2);
  k_stats2<<<2, 256, 0, stream>>>(partials2, 512, 4096.f, mu2, rs2);
  k_final<<<512, 256, 0, stream>>>(outpre, mu2, rs2, out);
}